// Round 7
// baseline (2366.203 us; speedup 1.0000x reference)
//
#include <hip/hip_runtime.h>
#include <hip/hip_fp16.h>

#define HD 384
#define HHD 192

using bf16x8 = __attribute__((ext_vector_type(8))) short;
using f32x4  = __attribute__((ext_vector_type(4))) float;

__device__ __forceinline__ float gelu_f(float x) {
    return 0.5f * x * (1.0f + erff(x * 0.70710678118654752f));
}

__device__ __forceinline__ float sigmoid_f(float x) {
    return 1.0f / (1.0f + expf(-x));
}

// ---------------- CSR build ----------------
__global__ __launch_bounds__(256) void hist_rows(
        const int* __restrict__ rows, int* __restrict__ cnt, int nnz) {
    int e = blockIdx.x * blockDim.x + threadIdx.x;
    if (e < nnz) atomicAdd(&cnt[rows[e]], 1);
}

__global__ __launch_bounds__(256) void scan_local(
        const int* __restrict__ cnt, int* __restrict__ rp,
        int* __restrict__ bsum, int n) {
    __shared__ int wsum[4];
    int i = blockIdx.x * 256 + threadIdx.x;
    int lane = threadIdx.x & 63, wv = threadIdx.x >> 6;
    int v = (i < n) ? cnt[i] : 0;
    int s = v;
    #pragma unroll
    for (int o = 1; o < 64; o <<= 1) {
        int t = __shfl_up(s, o);
        if (lane >= o) s += t;
    }
    if (lane == 63) wsum[wv] = s;
    __syncthreads();
    int woff = 0;
    for (int w = 0; w < wv; ++w) woff += wsum[w];
    if (i < n) rp[i] = woff + s - v;
    if (threadIdx.x == 255) bsum[blockIdx.x] = woff + s;
}

__global__ __launch_bounds__(256) void scan_bsums(
        const int* __restrict__ bsum, int* __restrict__ boff,
        int nb, int* __restrict__ total_out) {
    __shared__ int tmp[256];
    int tid = threadIdx.x;
    int v = (tid < nb) ? bsum[tid] : 0;
    tmp[tid] = v;
    __syncthreads();
    for (int o = 1; o < 256; o <<= 1) {
        int t = (tid >= o) ? tmp[tid - o] : 0;
        __syncthreads();
        tmp[tid] += t;
        __syncthreads();
    }
    if (tid < nb) boff[tid] = tmp[tid] - v;
    if (tid == nb - 1) *total_out = tmp[tid];
}

__global__ __launch_bounds__(256) void scan_add(
        int* __restrict__ rp, const int* __restrict__ boff, int n) {
    int i = blockIdx.x * 256 + threadIdx.x;
    if (i < n) rp[i] += boff[i >> 8];
}

__global__ __launch_bounds__(256) void csr_scatter(
        const int* __restrict__ rows, const int* __restrict__ cols,
        const float* __restrict__ vals, const int* __restrict__ rp,
        int* __restrict__ fill, int* __restrict__ cp,
        float* __restrict__ vp, int nnz) {
    int e = blockIdx.x * blockDim.x + threadIdx.x;
    if (e >= nnz) return;
    int r = rows[e];
    int pos = rp[r] + atomicAdd(&fill[r], 1);
    cp[pos] = cols[e];
    vp[pos] = vals[e];
}

// ---------------- per-row column sort (sliding-window locality) ----------------
__global__ __launch_bounds__(256) void sort_rows(
        const int* __restrict__ rp, int* __restrict__ cp,
        float* __restrict__ vp, int n) {
    int r = blockIdx.x * blockDim.x + threadIdx.x;
    if (r >= n) return;
    int s = rp[r], e = rp[r + 1];
    for (int i = s + 1; i < e; ++i) {
        int c = cp[i];
        float v = vp[i];
        int j = i - 1;
        while (j >= s && cp[j] > c) {
            cp[j + 1] = cp[j];
            vp[j + 1] = vp[j];
            --j;
        }
        cp[j + 1] = c;
        vp[j + 1] = v;
    }
}

// ---------------- fp32 -> fp16 convert ----------------
__global__ __launch_bounds__(256) void cvt_fp16(
        const float* __restrict__ in, __half2* __restrict__ out, int n2) {
    int i = blockIdx.x * blockDim.x + threadIdx.x;
    if (i >= n2) return;
    float2 v = reinterpret_cast<const float2*>(in)[i];
    out[i] = __floats2half2_rn(v.x, v.y);
}

// ---------------- SpMM (CSR gather, fp16 table, fp16 out) ----------------
__global__ __launch_bounds__(384) void spmm_h2(
        const int* __restrict__ rp, const int* __restrict__ cp,
        const float* __restrict__ vp, const __half2* __restrict__ in,
        __half2* __restrict__ out, int nrows) {
    const int t  = threadIdx.x % HHD;
    const int r  = blockIdx.x * 2 + threadIdx.x / HHD;
    if (r >= nrows) return;
    const int s = rp[r], e = rp[r + 1];
    float ax = 0.f, ay = 0.f;
    for (int p = s; p < e; ++p) {
        int c = cp[p];
        float v = vp[p];
        float2 x = __half22float2(in[(size_t)c * HHD + t]);
        ax = fmaf(v, x.x, ax);
        ay = fmaf(v, x.y, ay);
    }
    out[(size_t)r * HHD + t] = __floats2half2_rn(ax, ay);
}

// ---------------- fused doc SpMM: docH0 = X@emb, docH = 0.35*docH0 + 0.65*X@h3 ----
__global__ __launch_bounds__(384) void spmm_doc2(
        const int* __restrict__ rp, const int* __restrict__ cp,
        const float* __restrict__ vp,
        const __half2* __restrict__ inH, const __half2* __restrict__ inE,
        float* __restrict__ docH, float* __restrict__ docH0, int nrows) {
    const int t  = threadIdx.x % HHD;
    const int r  = blockIdx.x * 2 + threadIdx.x / HHD;
    if (r >= nrows) return;
    const int s = rp[r], e = rp[r + 1];
    float hx = 0.f, hy = 0.f, ex = 0.f, ey = 0.f;
    for (int p = s; p < e; ++p) {
        int c = cp[p];
        float v = vp[p];
        float2 xh = __half22float2(inH[(size_t)c * HHD + t]);
        float2 xe = __half22float2(inE[(size_t)c * HHD + t]);
        hx = fmaf(v, xh.x, hx);
        hy = fmaf(v, xh.y, hy);
        ex = fmaf(v, xe.x, ex);
        ey = fmaf(v, xe.y, ey);
    }
    reinterpret_cast<float2*>(docH0)[(size_t)r * HHD + t] = make_float2(ex, ey);
    reinterpret_cast<float2*>(docH)[(size_t)r * HHD + t] =
        make_float2(0.35f * ex + 0.65f * hx, 0.35f * ey + 0.65f * hy);
}

// ---------------- weight pack: fp32 [K,N] -> fragment-layout hi/lo bf16 ----------------
__global__ __launch_bounds__(256) void pack_w(
        const float* __restrict__ W, unsigned short* __restrict__ out,
        int KS, int NS, int N) {
    int t = blockIdx.x * 256 + threadIdx.x;
    int total = KS * NS * 64;
    if (t >= total) return;
    int l = t & 63;
    int ns = (t >> 6) % NS;
    int ks = t / (64 * NS);
    int col = ns * 16 + (l & 15);
    int k0 = ks * 32 + 8 * (l >> 4);
    size_t obase = (size_t)t * 8;
    size_t pstride = (size_t)KS * NS * 512;
    #pragma unroll
    for (int e = 0; e < 8; ++e) {
        float f = W[(size_t)(k0 + e) * N + col];
        unsigned u = __float_as_uint(f);
        unsigned short h = (unsigned short)(u >> 16);
        float r = f - __uint_as_float(u & 0xFFFF0000u);
        unsigned short lo = (unsigned short)(__float_as_uint(r) >> 16);
        out[obase + e] = (unsigned short)h;
        out[pstride + obase + e] = lo;
    }
}

__device__ __forceinline__ void splitf(const float* f, bf16x8& h, bf16x8& l) {
    #pragma unroll
    for (int e = 0; e < 8; ++e) {
        unsigned u = __float_as_uint(f[e]);
        h[e] = (short)(unsigned short)(u >> 16);
        float r = f[e] - __uint_as_float(u & 0xFFFF0000u);
        l[e] = (short)(unsigned short)(__float_as_uint(r) >> 16);
    }
}

// ---------------- split-bf16 MFMA GEMM; 16-row M-tile/block, N split over 4 waves ----
// MODE 0: y = gelu(LN(A@W, gamma, beta))            (word GCN)
// MODE 1: out = gelu(A@W + bias)                    (gate1; A=[A1|A2])
// MODE 2: g = sigmoid(A@W + bias); out = g*aux1 + (1-g)*aux2
// MODE 3: out = LN(gelu(A@W + bias), gamma, beta)   (mlp1)
// MODE 4: v = gelu(A@W + bias); out = v @ aux1 + gamma  (mlp2 + classifier)
template<int MODE, int NS, int KS, int KSPLIT, bool A16, bool OUT16>
__global__ __launch_bounds__(256) void gemm_mfma(
        const float* __restrict__ A1, const float* __restrict__ A2,
        const unsigned short* __restrict__ Wp,
        const float* __restrict__ bias, const float* __restrict__ gamma,
        const float* __restrict__ beta,
        const float* __restrict__ aux1, const float* __restrict__ aux2,
        float* __restrict__ out, int M) {
    constexpr int N = NS * 16;
    constexpr int NSW = NS / 4;
    const int tid = threadIdx.x;
    const int wave = tid >> 6, l = tid & 63;
    const int row_base = blockIdx.x * 16;
    const int arow = row_base + (l & 15);
    const bool arow_ok = arow < M;
    const int koff = 8 * (l >> 4);
    const size_t pstride = (size_t)KS * NS * 512;

    __shared__ float ps[4][16], pq[4][16];
    __shared__ float mean_s[16], rstd_s[16];
    __shared__ float plg[4][16][2];

    f32x4 acc[NSW];
    #pragma unroll
    for (int ns = 0; ns < NSW; ++ns)
        acc[ns] = f32x4{0.f, 0.f, 0.f, 0.f};

    for (int ks = 0; ks < KS; ++ks) {
        const float* Ap;
        int ksl;
        if (ks < KSPLIT) { Ap = A1; ksl = ks; }
        else             { Ap = A2; ksl = ks - KSPLIT; }
        bf16x8 ah, al;
        if (arow_ok) {
            float f[8];
            if constexpr (A16) {
                const __half2* src = reinterpret_cast<const __half2*>(Ap)
                                     + ((size_t)arow * HD + ksl * 32 + koff) / 2;
                #pragma unroll
                for (int e = 0; e < 4; ++e) {
                    float2 v = __half22float2(src[e]);
                    f[2 * e]     = v.x;
                    f[2 * e + 1] = v.y;
                }
            } else {
                const float* src = Ap + (size_t)arow * HD + ksl * 32 + koff;
                float4 a0 = *reinterpret_cast<const float4*>(src);
                float4 a1 = *reinterpret_cast<const float4*>(src + 4);
                f[0] = a0.x; f[1] = a0.y; f[2] = a0.z; f[3] = a0.w;
                f[4] = a1.x; f[5] = a1.y; f[6] = a1.z; f[7] = a1.w;
            }
            splitf(f, ah, al);
        } else {
            #pragma unroll
            for (int e = 0; e < 8; ++e) { ah[e] = 0; al[e] = 0; }
        }
        const unsigned short* Bp = Wp + (size_t)ks * NS * 512
                                   + (size_t)wave * NSW * 512 + (size_t)l * 8;
        #pragma unroll
        for (int ns = 0; ns < NSW; ++ns) {
            bf16x8 bh = *reinterpret_cast<const bf16x8*>(Bp + ns * 512);
            bf16x8 bl = *reinterpret_cast<const bf16x8*>(Bp + pstride + ns * 512);
            acc[ns] = __builtin_amdgcn_mfma_f32_16x16x32_bf16(ah, bh, acc[ns], 0, 0, 0);
            acc[ns] = __builtin_amdgcn_mfma_f32_16x16x32_bf16(al, bh, acc[ns], 0, 0, 0);
            acc[ns] = __builtin_amdgcn_mfma_f32_16x16x32_bf16(ah, bl, acc[ns], 0, 0, 0);
        }
    }

    const int col_lane = l & 15;
    const int g4 = (l >> 4) * 4;
    constexpr float invN = 1.0f / (float)N;

    if constexpr (MODE == 0 || MODE == 3) {
        if constexpr (MODE == 3) {
            #pragma unroll
            for (int ns = 0; ns < NSW; ++ns) {
                float bb = bias[(wave * NSW + ns) * 16 + col_lane];
                #pragma unroll
                for (int r = 0; r < 4; ++r)
                    acc[ns][r] = gelu_f(acc[ns][r] + bb);
            }
        }
        float s[4] = {0.f, 0.f, 0.f, 0.f}, q[4] = {0.f, 0.f, 0.f, 0.f};
        #pragma unroll
        for (int ns = 0; ns < NSW; ++ns)
            #pragma unroll
            for (int r = 0; r < 4; ++r) {
                float v = acc[ns][r];
                s[r] += v;
                q[r] += v * v;
            }
        #pragma unroll
        for (int r = 0; r < 4; ++r) {
            #pragma unroll
            for (int m = 1; m < 16; m <<= 1) {
                s[r] += __shfl_xor(s[r], m);
                q[r] += __shfl_xor(q[r], m);
            }
        }
        if (col_lane == 0) {
            #pragma unroll
            for (int r = 0; r < 4; ++r) {
                ps[wave][g4 + r] = s[r];
                pq[wave][g4 + r] = q[r];
            }
        }
        __syncthreads();
        if (tid < 16) {
            float ss = ps[0][tid] + ps[1][tid] + ps[2][tid] + ps[3][tid];
            float qq = pq[0][tid] + pq[1][tid] + pq[2][tid] + pq[3][tid];
            float m = ss * invN;
            mean_s[tid] = m;
            rstd_s[tid] = rsqrtf(qq * invN - m * m + 1e-5f);
        }
        __syncthreads();
        #pragma unroll
        for (int ns = 0; ns < NSW; ++ns) {
            int col = (wave * NSW + ns) * 16 + col_lane;
            float gg = gamma[col], bb = beta[col];
            #pragma unroll
            for (int r = 0; r < 4; ++r) {
                int row = row_base + g4 + r;
                if (row < M) {
                    float y = (acc[ns][r] - mean_s[g4 + r]) * rstd_s[g4 + r] * gg + bb;
                    if constexpr (MODE == 0) {
                        y = gelu_f(y);
                        if constexpr (OUT16)
                            reinterpret_cast<__half*>(out)[(size_t)row * N + col] =
                                __float2half(y);
                        else
                            out[(size_t)row * N + col] = y;
                    } else {
                        out[(size_t)row * N + col] = y;
                    }
                }
            }
        }
    } else if constexpr (MODE == 1) {
        #pragma unroll
        for (int ns = 0; ns < NSW; ++ns) {
            int col = (wave * NSW + ns) * 16 + col_lane;
            float bb = bias[col];
            #pragma unroll
            for (int r = 0; r < 4; ++r) {
                int row = row_base + g4 + r;
                if (row < M)
                    out[(size_t)row * N + col] = gelu_f(acc[ns][r] + bb);
            }
        }
    } else if constexpr (MODE == 2) {
        #pragma unroll
        for (int ns = 0; ns < NSW; ++ns) {
            int col = (wave * NSW + ns) * 16 + col_lane;
            float bb = bias[col];
            #pragma unroll
            for (int r = 0; r < 4; ++r) {
                int row = row_base + g4 + r;
                if (row < M) {
                    float g = sigmoid_f(acc[ns][r] + bb);
                    float h1 = aux1[(size_t)row * N + col];
                    float h0 = aux2[(size_t)row * N + col];
                    out[(size_t)row * N + col] = g * h1 + (1.0f - g) * h0;
                }
            }
        }
    } else if constexpr (MODE == 4) {
        float lg0[4] = {0.f, 0.f, 0.f, 0.f}, lg1[4] = {0.f, 0.f, 0.f, 0.f};
        #pragma unroll
        for (int ns = 0; ns < NSW; ++ns) {
            int col = (wave * NSW + ns) * 16 + col_lane;
            float bb = bias[col];
            float c0 = aux1[col * 2 + 0];
            float c1 = aux1[col * 2 + 1];
            #pragma unroll
            for (int r = 0; r < 4; ++r) {
                float v = gelu_f(acc[ns][r] + bb);
                lg0[r] = fmaf(v, c0, lg0[r]);
                lg1[r] = fmaf(v, c1, lg1[r]);
            }
        }
        #pragma unroll
        for (int r = 0; r < 4; ++r) {
            #pragma unroll
            for (int m = 1; m < 16; m <<= 1) {
                lg0[r] += __shfl_xor(lg0[r], m);
                lg1[r] += __shfl_xor(lg1[r], m);
            }
        }
        if (col_lane == 0) {
            #pragma unroll
            for (int r = 0; r < 4; ++r) {
                plg[wave][g4 + r][0] = lg0[r];
                plg[wave][g4 + r][1] = lg1[r];
            }
        }
        __syncthreads();
        if (tid < 32) {
            int rloc = tid >> 1, c = tid & 1;
            int row = row_base + rloc;
            if (row < M) {
                float t = plg[0][rloc][c] + plg[1][rloc][c]
                        + plg[2][rloc][c] + plg[3][rloc][c];
                out[(size_t)row * 2 + c] = t + gamma[c];
            }
        }
    }
}

static void build_csr(const int* rows, const int* cols, const float* vals,
                      int nnz, int n, int* rp, int* cp, float* vp,
                      int* cnt, int* bsum, int* boff, hipStream_t stream) {
    hipMemsetAsync(cnt, 0, (size_t)n * sizeof(int), stream);
    hist_rows<<<(nnz + 255) / 256, 256, 0, stream>>>(rows, cnt, nnz);
    int nb = (n + 255) / 256;
    scan_local<<<nb, 256, 0, stream>>>(cnt, rp, bsum, n);
    scan_bsums<<<1, 256, 0, stream>>>(bsum, boff, nb, rp + n);
    scan_add<<<nb, 256, 0, stream>>>(rp, boff, n);
    hipMemsetAsync(cnt, 0, (size_t)n * sizeof(int), stream);
    csr_scatter<<<(nnz + 255) / 256, 256, 0, stream>>>(rows, cols, vals, rp, cnt, cp, vp, nnz);
    sort_rows<<<(n + 255) / 256, 256, 0, stream>>>(rp, cp, vp, n);
}

extern "C" void kernel_launch(void* const* d_in, const int* in_sizes, int n_in,
                              void* d_out, int out_size, void* d_ws, size_t ws_size,
                              hipStream_t stream) {
    const int*   A_rows = (const int*)  d_in[0];
    const int*   A_cols = (const int*)  d_in[1];
    const float* A_vals = (const float*)d_in[2];
    const int*   X_rows = (const int*)  d_in[3];
    const int*   X_cols = (const int*)  d_in[4];
    const float* X_vals = (const float*)d_in[5];
    const float* emb    = (const float*)d_in[7];
    const float* W1     = (const float*)d_in[8];
    const float* W2     = (const float*)d_in[9];
    const float* W3     = (const float*)d_in[10];
    const float* g1     = (const float*)d_in[11];
    const float* b1     = (const float*)d_in[12];
    const float* g2     = (const float*)d_in[13];
    const float* b2     = (const float*)d_in[14];
    const float* g3     = (const float*)d_in[15];
    const float* b3     = (const float*)d_in[16];
    const float* mW1    = (const float*)d_in[17];
    const float* mb1    = (const float*)d_in[18];
    const float* mg     = (const float*)d_in[19];
    const float* mbn    = (const float*)d_in[20];
    const float* mW2    = (const float*)d_in[21];
    const float* mb2    = (const float*)d_in[22];
    const float* cW     = (const float*)d_in[23];
    const float* cb     = (const float*)d_in[24];
    const float* gW1    = (const float*)d_in[25];
    const float* gb1    = (const float*)d_in[26];
    const float* gW2    = (const float*)d_in[27];
    const float* gb2    = (const float*)d_in[28];

    const int E_   = in_sizes[0];
    const int NNZ_ = in_sizes[3];
    const int N_   = in_sizes[7] / HD;
    const int D_   = out_size / 2;

    // ---- workspace layout ----
    // fp16 buffers (each N*H halfs = 30.72 MB); doc-phase fp32 aliases overlap exactly
    __half2* emb16 = (__half2*)d_ws;                   // [N,H] fp16 | later t1 [D,H] f32
    __half2* Ba    = emb16 + (size_t)N_ * HHD;         // ping     | later docH/un f32
    __half2* Bb    = Ba    + (size_t)N_ * HHD;         // pong     | later dmix f32
    float* docH0 = (float*)(Bb + (size_t)N_ * HHD);    // [D,H] f32
    int*   A_rp = (int*)(docH0 + (size_t)D_ * HD);
    int*   A_cp = A_rp + (N_ + 1);
    float* A_vp = (float*)(A_cp + E_);
    int*   X_rp = (int*)(A_vp + E_);
    int*   X_cp = X_rp + (D_ + 1);
    float* X_vp = (float*)(X_cp + NNZ_);
    int*   cnt  = (int*)(X_vp + NNZ_);
    int*   bsum = cnt + N_;
    int*   boff = bsum + 256;
    size_t pk_off = ((size_t)(boff + 256 - (int*)d_ws) + 7) & ~(size_t)7;
    unsigned short* packs = (unsigned short*)((float*)d_ws + pk_off);
    const size_t SZ_SQ = (size_t)2 * HD * HD;
    unsigned short* p_W1  = packs;
    unsigned short* p_W2  = p_W1  + SZ_SQ;
    unsigned short* p_W3  = p_W2  + SZ_SQ;
    unsigned short* p_gW2 = p_W3  + SZ_SQ;
    unsigned short* p_mW1 = p_gW2 + SZ_SQ;
    unsigned short* p_gW1 = p_mW1 + SZ_SQ;
    unsigned short* p_mW2 = p_gW1 + (size_t)2 * 2 * HD * HD;

    // doc-phase fp32 aliases
    float* docH  = (float*)Ba;     // written by spmm_doc2 (Ba's fp16 contents dead)
    float* t1    = (float*)emb16;  // written by gate1 (emb16 dead after spmm_doc2)
    float* dmix  = (float*)Bb;     // written by gate2 (h3 dead)
    float* un    = (float*)Ba;     // written by mlp1 (docH dead after gate2)
    float* logits = (float*)d_out;

    const int word_grid = (N_ + 15) / 16;
    const int doc_grid  = (D_ + 15) / 16;

    // ---- pack weights ----
    pack_w<<<(12 * 24 * 64 + 255) / 256, 256, 0, stream>>>(W1,  p_W1,  12, 24, HD);
    pack_w<<<(12 * 24 * 64 + 255) / 256, 256, 0, stream>>>(W2,  p_W2,  12, 24, HD);
    pack_w<<<(12 * 24 * 64 + 255) / 256, 256, 0, stream>>>(W3,  p_W3,  12, 24, HD);
    pack_w<<<(12 * 24 * 64 + 255) / 256, 256, 0, stream>>>(gW2, p_gW2, 12, 24, HD);
    pack_w<<<(12 * 24 * 64 + 255) / 256, 256, 0, stream>>>(mW1, p_mW1, 12, 24, HD);
    pack_w<<<(24 * 24 * 64 + 255) / 256, 256, 0, stream>>>(gW1, p_gW1, 24, 24, HD);
    pack_w<<<(12 * 12 * 64 + 255) / 256, 256, 0, stream>>>(mW2, p_mW2, 12, 12, HHD);

    // ---- emb -> fp16 ----
    cvt_fp16<<<((N_ * HHD) + 255) / 256, 256, 0, stream>>>(emb, emb16, N_ * HHD);

    // ---- build CSR (column-sorted rows) ----
    build_csr(A_rows, A_cols, A_vals, E_, N_, A_rp, A_cp, A_vp, cnt, bsum, boff, stream);
    build_csr(X_rows, X_cols, X_vals, NNZ_, D_, X_rp, X_cp, X_vp, cnt, bsum, boff, stream);

    // ---- GCN blocks (fp16 ping-pong: spmm fp16->fp16, gemm fp16->fp16) ----
    spmm_h2<<<(N_ + 1) / 2, 384, 0, stream>>>(A_rp, A_cp, A_vp, emb16, Ba, N_);
    gemm_mfma<0, 24, 12, 12, true, true><<<word_grid, 256, 0, stream>>>(
        (const float*)Ba, nullptr, p_W1, nullptr, g1, b1, nullptr, nullptr, (float*)Bb, N_);
    spmm_h2<<<(N_ + 1) / 2, 384, 0, stream>>>(A_rp, A_cp, A_vp, Bb, Ba, N_);
    gemm_mfma<0, 24, 12, 12, true, true><<<word_grid, 256, 0, stream>>>(
        (const float*)Ba, nullptr, p_W2, nullptr, g2, b2, nullptr, nullptr, (float*)Bb, N_);
    spmm_h2<<<(N_ + 1) / 2, 384, 0, stream>>>(A_rp, A_cp, A_vp, Bb, Ba, N_);
    gemm_mfma<0, 24, 12, 12, true, true><<<word_grid, 256, 0, stream>>>(
        (const float*)Ba, nullptr, p_W3, nullptr, g3, b3, nullptr, nullptr, (float*)Bb, N_);

    // ---- fused doc aggregation: docH0 = X@emb; docH = 0.35*docH0 + 0.65*X@h3 ----
    spmm_doc2<<<(D_ + 1) / 2, 384, 0, stream>>>(X_rp, X_cp, X_vp, Bb, emb16,
                                                docH, docH0, D_);

    // ---- doc head ----
    gemm_mfma<1, 24, 24, 12, false, false><<<doc_grid, 256, 0, stream>>>(
        docH, docH0, p_gW1, gb1, nullptr, nullptr, nullptr, nullptr, t1, D_);
    gemm_mfma<2, 24, 12, 12, false, false><<<doc_grid, 256, 0, stream>>>(
        t1, nullptr, p_gW2, gb2, nullptr, nullptr, docH, docH0, dmix, D_);
    gemm_mfma<3, 24, 12, 12, false, false><<<doc_grid, 256, 0, stream>>>(
        dmix, nullptr, p_mW1, mb1, mg, mbn, nullptr, nullptr, un, D_);
    gemm_mfma<4, 12, 12, 12, false, false><<<doc_grid, 256, 0, stream>>>(
        un, nullptr, p_mW2, mb2, cb, nullptr, cW, nullptr, logits, D_);
}

// Round 8
// 1747.548 us; speedup vs baseline: 1.3540x; 1.3540x over previous
//
#include <hip/hip_runtime.h>
#include <hip/hip_fp16.h>

#define HD 384
#define HHD 192
#define SORT_CAP 128

using bf16x8 = __attribute__((ext_vector_type(8))) short;
using f32x4  = __attribute__((ext_vector_type(4))) float;

__device__ __forceinline__ float gelu_f(float x) {
    return 0.5f * x * (1.0f + erff(x * 0.70710678118654752f));
}

__device__ __forceinline__ float sigmoid_f(float x) {
    return 1.0f / (1.0f + expf(-x));
}

// ---------------- CSR build ----------------
__global__ __launch_bounds__(256) void hist_rows(
        const int* __restrict__ rows, int* __restrict__ cnt, int nnz) {
    int e = blockIdx.x * blockDim.x + threadIdx.x;
    if (e < nnz) atomicAdd(&cnt[rows[e]], 1);
}

__global__ __launch_bounds__(256) void scan_local(
        const int* __restrict__ cnt, int* __restrict__ rp,
        int* __restrict__ bsum, int n) {
    __shared__ int wsum[4];
    int i = blockIdx.x * 256 + threadIdx.x;
    int lane = threadIdx.x & 63, wv = threadIdx.x >> 6;
    int v = (i < n) ? cnt[i] : 0;
    int s = v;
    #pragma unroll
    for (int o = 1; o < 64; o <<= 1) {
        int t = __shfl_up(s, o);
        if (lane >= o) s += t;
    }
    if (lane == 63) wsum[wv] = s;
    __syncthreads();
    int woff = 0;
    for (int w = 0; w < wv; ++w) woff += wsum[w];
    if (i < n) rp[i] = woff + s - v;
    if (threadIdx.x == 255) bsum[blockIdx.x] = woff + s;
}

__global__ __launch_bounds__(256) void scan_bsums(
        const int* __restrict__ bsum, int* __restrict__ boff,
        int nb, int* __restrict__ total_out) {
    __shared__ int tmp[256];
    int tid = threadIdx.x;
    int v = (tid < nb) ? bsum[tid] : 0;
    tmp[tid] = v;
    __syncthreads();
    for (int o = 1; o < 256; o <<= 1) {
        int t = (tid >= o) ? tmp[tid - o] : 0;
        __syncthreads();
        tmp[tid] += t;
        __syncthreads();
    }
    if (tid < nb) boff[tid] = tmp[tid] - v;
    if (tid == nb - 1) *total_out = tmp[tid];
}

__global__ __launch_bounds__(256) void scan_add(
        int* __restrict__ rp, const int* __restrict__ boff, int n) {
    int i = blockIdx.x * 256 + threadIdx.x;
    if (i < n) rp[i] += boff[i >> 8];
}

__global__ __launch_bounds__(256) void csr_scatter(
        const int* __restrict__ rows, const int* __restrict__ cols,
        const float* __restrict__ vals, const int* __restrict__ rp,
        int* __restrict__ fill, int* __restrict__ cp,
        float* __restrict__ vp, int nnz) {
    int e = blockIdx.x * blockDim.x + threadIdx.x;
    if (e >= nnz) return;
    int r = rows[e];
    int pos = rp[r] + atomicAdd(&fill[r], 1);
    cp[pos] = cols[e];
    vp[pos] = vals[e];
}

// ---------------- wave-parallel per-row column sort (odd-even in LDS) ----------------
__global__ __launch_bounds__(256) void sort_rows_wave(
        const int* __restrict__ rp, int* __restrict__ cp,
        float* __restrict__ vp, int n) {
    __shared__ int   sc[4][SORT_CAP];
    __shared__ float sv[4][SORT_CAP];
    __shared__ int maxlen_s;
    const int wv = threadIdx.x >> 6, lane = threadIdx.x & 63;
    const int r = blockIdx.x * 4 + wv;
    int s = 0, len = 0;
    if (r < n) { s = rp[r]; len = rp[r + 1] - s; }
    if (len > SORT_CAP) {
        // impossible for this problem's stats; serial fallback for safety
        if (lane == 0) {
            for (int i = s + 1; i < s + len; ++i) {
                int c = cp[i]; float v = vp[i];
                int j = i - 1;
                while (j >= s && cp[j] > c) { cp[j+1] = cp[j]; vp[j+1] = vp[j]; --j; }
                cp[j+1] = c; vp[j+1] = v;
            }
        }
        len = 0;
    }
    if (threadIdx.x == 0) maxlen_s = 0;
    for (int i = lane; i < len; i += 64) {
        sc[wv][i] = cp[s + i];
        sv[wv][i] = vp[s + i];
    }
    __syncthreads();
    if (lane == 0) atomicMax(&maxlen_s, len);
    __syncthreads();
    const int phases = maxlen_s;
    for (int t = 0; t < phases; ++t) {
        const int start = t & 1;
        int a = start + 2 * lane;
        int b = a + 1;
        if (b < len) {
            int ca = sc[wv][a], cb = sc[wv][b];
            if (ca > cb) {
                sc[wv][a] = cb; sc[wv][b] = ca;
                float va = sv[wv][a];
                sv[wv][a] = sv[wv][b]; sv[wv][b] = va;
            }
        }
        __syncthreads();
    }
    for (int i = lane; i < len; i += 64) {
        cp[s + i] = sc[wv][i];
        vp[s + i] = sv[wv][i];
    }
}

// ---------------- fp32 -> fp16 convert ----------------
__global__ __launch_bounds__(256) void cvt_fp16(
        const float* __restrict__ in, __half2* __restrict__ out, int n2) {
    int i = blockIdx.x * blockDim.x + threadIdx.x;
    if (i >= n2) return;
    float2 v = reinterpret_cast<const float2*>(in)[i];
    out[i] = __floats2half2_rn(v.x, v.y);
}

// ---------------- SpMM (CSR gather, fp16 table, fp16 out) ----------------
__global__ __launch_bounds__(384) void spmm_h2(
        const int* __restrict__ rp, const int* __restrict__ cp,
        const float* __restrict__ vp, const __half2* __restrict__ in,
        __half2* __restrict__ out, int nrows) {
    const int t  = threadIdx.x % HHD;
    const int r  = blockIdx.x * 2 + threadIdx.x / HHD;
    if (r >= nrows) return;
    const int s = rp[r], e = rp[r + 1];
    float ax = 0.f, ay = 0.f;
    for (int p = s; p < e; ++p) {
        int c = cp[p];
        float v = vp[p];
        float2 x = __half22float2(in[(size_t)c * HHD + t]);
        ax = fmaf(v, x.x, ax);
        ay = fmaf(v, x.y, ay);
    }
    out[(size_t)r * HHD + t] = __floats2half2_rn(ax, ay);
}

// ---------------- fused doc SpMM: docH0 = X@emb, docH = 0.35*docH0 + 0.65*X@h3 ----
__global__ __launch_bounds__(384) void spmm_doc2(
        const int* __restrict__ rp, const int* __restrict__ cp,
        const float* __restrict__ vp,
        const __half2* __restrict__ inH, const __half2* __restrict__ inE,
        float* __restrict__ docH, float* __restrict__ docH0, int nrows) {
    const int t  = threadIdx.x % HHD;
    const int r  = blockIdx.x * 2 + threadIdx.x / HHD;
    if (r >= nrows) return;
    const int s = rp[r], e = rp[r + 1];
    float hx = 0.f, hy = 0.f, ex = 0.f, ey = 0.f;
    for (int p = s; p < e; ++p) {
        int c = cp[p];
        float v = vp[p];
        float2 xh = __half22float2(inH[(size_t)c * HHD + t]);
        float2 xe = __half22float2(inE[(size_t)c * HHD + t]);
        hx = fmaf(v, xh.x, hx);
        hy = fmaf(v, xh.y, hy);
        ex = fmaf(v, xe.x, ex);
        ey = fmaf(v, xe.y, ey);
    }
    reinterpret_cast<float2*>(docH0)[(size_t)r * HHD + t] = make_float2(ex, ey);
    reinterpret_cast<float2*>(docH)[(size_t)r * HHD + t] =
        make_float2(0.35f * ex + 0.65f * hx, 0.35f * ey + 0.65f * hy);
}

// ---------------- weight pack: fp32 [K,N] -> fragment-layout hi/lo bf16 ----------------
__global__ __launch_bounds__(256) void pack_w(
        const float* __restrict__ W, unsigned short* __restrict__ out,
        int KS, int NS, int N) {
    int t = blockIdx.x * 256 + threadIdx.x;
    int total = KS * NS * 64;
    if (t >= total) return;
    int l = t & 63;
    int ns = (t >> 6) % NS;
    int ks = t / (64 * NS);
    int col = ns * 16 + (l & 15);
    int k0 = ks * 32 + 8 * (l >> 4);
    size_t obase = (size_t)t * 8;
    size_t pstride = (size_t)KS * NS * 512;
    #pragma unroll
    for (int e = 0; e < 8; ++e) {
        float f = W[(size_t)(k0 + e) * N + col];
        unsigned u = __float_as_uint(f);
        unsigned short h = (unsigned short)(u >> 16);
        float r = f - __uint_as_float(u & 0xFFFF0000u);
        unsigned short lo = (unsigned short)(__float_as_uint(r) >> 16);
        out[obase + e] = (unsigned short)h;
        out[pstride + obase + e] = lo;
    }
}

__device__ __forceinline__ void splitf(const float* f, bf16x8& h, bf16x8& l) {
    #pragma unroll
    for (int e = 0; e < 8; ++e) {
        unsigned u = __float_as_uint(f[e]);
        h[e] = (short)(unsigned short)(u >> 16);
        float r = f[e] - __uint_as_float(u & 0xFFFF0000u);
        l[e] = (short)(unsigned short)(__float_as_uint(r) >> 16);
    }
}

// ---------------- split-bf16 MFMA GEMM; 16-row M-tile/block, N split over 4 waves ----
// MODE 0: y = gelu(LN(A@W, gamma, beta))            (word GCN)
// MODE 1: out = gelu(A@W + bias)                    (gate1; A=[A1|A2])
// MODE 2: g = sigmoid(A@W + bias); out = g*aux1 + (1-g)*aux2
// MODE 3: out = LN(gelu(A@W + bias), gamma, beta)   (mlp1)
// MODE 4: v = gelu(A@W + bias); out = v @ aux1 + gamma  (mlp2 + classifier)
template<int MODE, int NS, int KS, int KSPLIT, bool A16, bool OUT16>
__global__ __launch_bounds__(256) void gemm_mfma(
        const float* __restrict__ A1, const float* __restrict__ A2,
        const unsigned short* __restrict__ Wp,
        const float* __restrict__ bias, const float* __restrict__ gamma,
        const float* __restrict__ beta,
        const float* __restrict__ aux1, const float* __restrict__ aux2,
        float* __restrict__ out, int M) {
    constexpr int N = NS * 16;
    constexpr int NSW = NS / 4;
    const int tid = threadIdx.x;
    const int wave = tid >> 6, l = tid & 63;
    const int row_base = blockIdx.x * 16;
    const int arow = row_base + (l & 15);
    const bool arow_ok = arow < M;
    const int koff = 8 * (l >> 4);
    const size_t pstride = (size_t)KS * NS * 512;

    __shared__ float ps[4][16], pq[4][16];
    __shared__ float mean_s[16], rstd_s[16];
    __shared__ float plg[4][16][2];

    f32x4 acc[NSW];
    #pragma unroll
    for (int ns = 0; ns < NSW; ++ns)
        acc[ns] = f32x4{0.f, 0.f, 0.f, 0.f};

    for (int ks = 0; ks < KS; ++ks) {
        const float* Ap;
        int ksl;
        if (ks < KSPLIT) { Ap = A1; ksl = ks; }
        else             { Ap = A2; ksl = ks - KSPLIT; }
        bf16x8 ah, al;
        if (arow_ok) {
            float f[8];
            if constexpr (A16) {
                const __half2* src = reinterpret_cast<const __half2*>(Ap)
                                     + ((size_t)arow * HD + ksl * 32 + koff) / 2;
                #pragma unroll
                for (int e = 0; e < 4; ++e) {
                    float2 v = __half22float2(src[e]);
                    f[2 * e]     = v.x;
                    f[2 * e + 1] = v.y;
                }
            } else {
                const float* src = Ap + (size_t)arow * HD + ksl * 32 + koff;
                float4 a0 = *reinterpret_cast<const float4*>(src);
                float4 a1 = *reinterpret_cast<const float4*>(src + 4);
                f[0] = a0.x; f[1] = a0.y; f[2] = a0.z; f[3] = a0.w;
                f[4] = a1.x; f[5] = a1.y; f[6] = a1.z; f[7] = a1.w;
            }
            splitf(f, ah, al);
        } else {
            #pragma unroll
            for (int e = 0; e < 8; ++e) { ah[e] = 0; al[e] = 0; }
        }
        const unsigned short* Bp = Wp + (size_t)ks * NS * 512
                                   + (size_t)wave * NSW * 512 + (size_t)l * 8;
        #pragma unroll
        for (int ns = 0; ns < NSW; ++ns) {
            bf16x8 bh = *reinterpret_cast<const bf16x8*>(Bp + ns * 512);
            bf16x8 bl = *reinterpret_cast<const bf16x8*>(Bp + pstride + ns * 512);
            acc[ns] = __builtin_amdgcn_mfma_f32_16x16x32_bf16(ah, bh, acc[ns], 0, 0, 0);
            acc[ns] = __builtin_amdgcn_mfma_f32_16x16x32_bf16(al, bh, acc[ns], 0, 0, 0);
            acc[ns] = __builtin_amdgcn_mfma_f32_16x16x32_bf16(ah, bl, acc[ns], 0, 0, 0);
        }
    }

    const int col_lane = l & 15;
    const int g4 = (l >> 4) * 4;
    constexpr float invN = 1.0f / (float)N;

    if constexpr (MODE == 0 || MODE == 3) {
        if constexpr (MODE == 3) {
            #pragma unroll
            for (int ns = 0; ns < NSW; ++ns) {
                float bb = bias[(wave * NSW + ns) * 16 + col_lane];
                #pragma unroll
                for (int r = 0; r < 4; ++r)
                    acc[ns][r] = gelu_f(acc[ns][r] + bb);
            }
        }
        float s[4] = {0.f, 0.f, 0.f, 0.f}, q[4] = {0.f, 0.f, 0.f, 0.f};
        #pragma unroll
        for (int ns = 0; ns < NSW; ++ns)
            #pragma unroll
            for (int r = 0; r < 4; ++r) {
                float v = acc[ns][r];
                s[r] += v;
                q[r] += v * v;
            }
        #pragma unroll
        for (int r = 0; r < 4; ++r) {
            #pragma unroll
            for (int m = 1; m < 16; m <<= 1) {
                s[r] += __shfl_xor(s[r], m);
                q[r] += __shfl_xor(q[r], m);
            }
        }
        if (col_lane == 0) {
            #pragma unroll
            for (int r = 0; r < 4; ++r) {
                ps[wave][g4 + r] = s[r];
                pq[wave][g4 + r] = q[r];
            }
        }
        __syncthreads();
        if (tid < 16) {
            float ss = ps[0][tid] + ps[1][tid] + ps[2][tid] + ps[3][tid];
            float qq = pq[0][tid] + pq[1][tid] + pq[2][tid] + pq[3][tid];
            float m = ss * invN;
            mean_s[tid] = m;
            rstd_s[tid] = rsqrtf(qq * invN - m * m + 1e-5f);
        }
        __syncthreads();
        #pragma unroll
        for (int ns = 0; ns < NSW; ++ns) {
            int col = (wave * NSW + ns) * 16 + col_lane;
            float gg = gamma[col], bb = beta[col];
            #pragma unroll
            for (int r = 0; r < 4; ++r) {
                int row = row_base + g4 + r;
                if (row < M) {
                    float y = (acc[ns][r] - mean_s[g4 + r]) * rstd_s[g4 + r] * gg + bb;
                    if constexpr (MODE == 0) {
                        y = gelu_f(y);
                        if constexpr (OUT16)
                            reinterpret_cast<__half*>(out)[(size_t)row * N + col] =
                                __float2half(y);
                        else
                            out[(size_t)row * N + col] = y;
                    } else {
                        out[(size_t)row * N + col] = y;
                    }
                }
            }
        }
    } else if constexpr (MODE == 1) {
        #pragma unroll
        for (int ns = 0; ns < NSW; ++ns) {
            int col = (wave * NSW + ns) * 16 + col_lane;
            float bb = bias[col];
            #pragma unroll
            for (int r = 0; r < 4; ++r) {
                int row = row_base + g4 + r;
                if (row < M)
                    out[(size_t)row * N + col] = gelu_f(acc[ns][r] + bb);
            }
        }
    } else if constexpr (MODE == 2) {
        #pragma unroll
        for (int ns = 0; ns < NSW; ++ns) {
            int col = (wave * NSW + ns) * 16 + col_lane;
            float bb = bias[col];
            #pragma unroll
            for (int r = 0; r < 4; ++r) {
                int row = row_base + g4 + r;
                if (row < M) {
                    float g = sigmoid_f(acc[ns][r] + bb);
                    float h1 = aux1[(size_t)row * N + col];
                    float h0 = aux2[(size_t)row * N + col];
                    out[(size_t)row * N + col] = g * h1 + (1.0f - g) * h0;
                }
            }
        }
    } else if constexpr (MODE == 4) {
        float lg0[4] = {0.f, 0.f, 0.f, 0.f}, lg1[4] = {0.f, 0.f, 0.f, 0.f};
        #pragma unroll
        for (int ns = 0; ns < NSW; ++ns) {
            int col = (wave * NSW + ns) * 16 + col_lane;
            float bb = bias[col];
            float c0 = aux1[col * 2 + 0];
            float c1 = aux1[col * 2 + 1];
            #pragma unroll
            for (int r = 0; r < 4; ++r) {
                float v = gelu_f(acc[ns][r] + bb);
                lg0[r] = fmaf(v, c0, lg0[r]);
                lg1[r] = fmaf(v, c1, lg1[r]);
            }
        }
        #pragma unroll
        for (int r = 0; r < 4; ++r) {
            #pragma unroll
            for (int m = 1; m < 16; m <<= 1) {
                lg0[r] += __shfl_xor(lg0[r], m);
                lg1[r] += __shfl_xor(lg1[r], m);
            }
        }
        if (col_lane == 0) {
            #pragma unroll
            for (int r = 0; r < 4; ++r) {
                plg[wave][g4 + r][0] = lg0[r];
                plg[wave][g4 + r][1] = lg1[r];
            }
        }
        __syncthreads();
        if (tid < 32) {
            int rloc = tid >> 1, c = tid & 1;
            int row = row_base + rloc;
            if (row < M) {
                float t = plg[0][rloc][c] + plg[1][rloc][c]
                        + plg[2][rloc][c] + plg[3][rloc][c];
                out[(size_t)row * 2 + c] = t + gamma[c];
            }
        }
    }
}

static void build_csr(const int* rows, const int* cols, const float* vals,
                      int nnz, int n, int* rp, int* cp, float* vp,
                      int* cnt, int* bsum, int* boff, hipStream_t stream) {
    hipMemsetAsync(cnt, 0, (size_t)n * sizeof(int), stream);
    hist_rows<<<(nnz + 255) / 256, 256, 0, stream>>>(rows, cnt, nnz);
    int nb = (n + 255) / 256;
    scan_local<<<nb, 256, 0, stream>>>(cnt, rp, bsum, n);
    scan_bsums<<<1, 256, 0, stream>>>(bsum, boff, nb, rp + n);
    scan_add<<<nb, 256, 0, stream>>>(rp, boff, n);
    hipMemsetAsync(cnt, 0, (size_t)n * sizeof(int), stream);
    csr_scatter<<<(nnz + 255) / 256, 256, 0, stream>>>(rows, cols, vals, rp, cnt, cp, vp, nnz);
    sort_rows_wave<<<(n + 3) / 4, 256, 0, stream>>>(rp, cp, vp, n);
}

extern "C" void kernel_launch(void* const* d_in, const int* in_sizes, int n_in,
                              void* d_out, int out_size, void* d_ws, size_t ws_size,
                              hipStream_t stream) {
    const int*   A_rows = (const int*)  d_in[0];
    const int*   A_cols = (const int*)  d_in[1];
    const float* A_vals = (const float*)d_in[2];
    const int*   X_rows = (const int*)  d_in[3];
    const int*   X_cols = (const int*)  d_in[4];
    const float* X_vals = (const float*)d_in[5];
    const float* emb    = (const float*)d_in[7];
    const float* W1     = (const float*)d_in[8];
    const float* W2     = (const float*)d_in[9];
    const float* W3     = (const float*)d_in[10];
    const float* g1     = (const float*)d_in[11];
    const float* b1     = (const float*)d_in[12];
    const float* g2     = (const float*)d_in[13];
    const float* b2     = (const float*)d_in[14];
    const float* g3     = (const float*)d_in[15];
    const float* b3     = (const float*)d_in[16];
    const float* mW1    = (const float*)d_in[17];
    const float* mb1    = (const float*)d_in[18];
    const float* mg     = (const float*)d_in[19];
    const float* mbn    = (const float*)d_in[20];
    const float* mW2    = (const float*)d_in[21];
    const float* mb2    = (const float*)d_in[22];
    const float* cW     = (const float*)d_in[23];
    const float* cb     = (const float*)d_in[24];
    const float* gW1    = (const float*)d_in[25];
    const float* gb1    = (const float*)d_in[26];
    const float* gW2    = (const float*)d_in[27];
    const float* gb2    = (const float*)d_in[28];

    const int E_   = in_sizes[0];
    const int NNZ_ = in_sizes[3];
    const int N_   = in_sizes[7] / HD;
    const int D_   = out_size / 2;

    // ---- workspace layout ----
    __half2* emb16 = (__half2*)d_ws;                   // [N,H] fp16 | later t1 [D,H] f32
    __half2* Ba    = emb16 + (size_t)N_ * HHD;         // ping     | later docH/un f32
    __half2* Bb    = Ba    + (size_t)N_ * HHD;         // pong     | later dmix f32
    float* docH0 = (float*)(Bb + (size_t)N_ * HHD);    // [D,H] f32
    int*   A_rp = (int*)(docH0 + (size_t)D_ * HD);
    int*   A_cp = A_rp + (N_ + 1);
    float* A_vp = (float*)(A_cp + E_);
    int*   X_rp = (int*)(A_vp + E_);
    int*   X_cp = X_rp + (D_ + 1);
    float* X_vp = (float*)(X_cp + NNZ_);
    int*   cnt  = (int*)(X_vp + NNZ_);
    int*   bsum = cnt + N_;
    int*   boff = bsum + 256;
    size_t pk_off = ((size_t)(boff + 256 - (int*)d_ws) + 7) & ~(size_t)7;
    unsigned short* packs = (unsigned short*)((float*)d_ws + pk_off);
    const size_t SZ_SQ = (size_t)2 * HD * HD;
    unsigned short* p_W1  = packs;
    unsigned short* p_W2  = p_W1  + SZ_SQ;
    unsigned short* p_W3  = p_W2  + SZ_SQ;
    unsigned short* p_gW2 = p_W3  + SZ_SQ;
    unsigned short* p_mW1 = p_gW2 + SZ_SQ;
    unsigned short* p_gW1 = p_mW1 + SZ_SQ;
    unsigned short* p_mW2 = p_gW1 + (size_t)2 * 2 * HD * HD;

    // doc-phase fp32 aliases
    float* docH  = (float*)Ba;
    float* t1    = (float*)emb16;
    float* dmix  = (float*)Bb;
    float* un    = (float*)Ba;
    float* logits = (float*)d_out;

    const int word_grid = (N_ + 15) / 16;
    const int doc_grid  = (D_ + 15) / 16;

    // ---- pack weights ----
    pack_w<<<(12 * 24 * 64 + 255) / 256, 256, 0, stream>>>(W1,  p_W1,  12, 24, HD);
    pack_w<<<(12 * 24 * 64 + 255) / 256, 256, 0, stream>>>(W2,  p_W2,  12, 24, HD);
    pack_w<<<(12 * 24 * 64 + 255) / 256, 256, 0, stream>>>(W3,  p_W3,  12, 24, HD);
    pack_w<<<(12 * 24 * 64 + 255) / 256, 256, 0, stream>>>(gW2, p_gW2, 12, 24, HD);
    pack_w<<<(12 * 24 * 64 + 255) / 256, 256, 0, stream>>>(mW1, p_mW1, 12, 24, HD);
    pack_w<<<(24 * 24 * 64 + 255) / 256, 256, 0, stream>>>(gW1, p_gW1, 24, 24, HD);
    pack_w<<<(12 * 12 * 64 + 255) / 256, 256, 0, stream>>>(mW2, p_mW2, 12, 12, HHD);

    // ---- emb -> fp16 ----
    cvt_fp16<<<((N_ * HHD) + 255) / 256, 256, 0, stream>>>(emb, emb16, N_ * HHD);

    // ---- build CSR (column-sorted rows) ----
    build_csr(A_rows, A_cols, A_vals, E_, N_, A_rp, A_cp, A_vp, cnt, bsum, boff, stream);
    build_csr(X_rows, X_cols, X_vals, NNZ_, D_, X_rp, X_cp, X_vp, cnt, bsum, boff, stream);

    // ---- GCN blocks (fp16 ping-pong) ----
    spmm_h2<<<(N_ + 1) / 2, 384, 0, stream>>>(A_rp, A_cp, A_vp, emb16, Ba, N_);
    gemm_mfma<0, 24, 12, 12, true, true><<<word_grid, 256, 0, stream>>>(
        (const float*)Ba, nullptr, p_W1, nullptr, g1, b1, nullptr, nullptr, (float*)Bb, N_);
    spmm_h2<<<(N_ + 1) / 2, 384, 0, stream>>>(A_rp, A_cp, A_vp, Bb, Ba, N_);
    gemm_mfma<0, 24, 12, 12, true, true><<<word_grid, 256, 0, stream>>>(
        (const float*)Ba, nullptr, p_W2, nullptr, g2, b2, nullptr, nullptr, (float*)Bb, N_);
    spmm_h2<<<(N_ + 1) / 2, 384, 0, stream>>>(A_rp, A_cp, A_vp, Bb, Ba, N_);
    gemm_mfma<0, 24, 12, 12, true, true><<<word_grid, 256, 0, stream>>>(
        (const float*)Ba, nullptr, p_W3, nullptr, g3, b3, nullptr, nullptr, (float*)Bb, N_);

    // ---- fused doc aggregation ----
    spmm_doc2<<<(D_ + 1) / 2, 384, 0, stream>>>(X_rp, X_cp, X_vp, Bb, emb16,
                                                docH, docH0, D_);

    // ---- doc head ----
    gemm_mfma<1, 24, 24, 12, false, false><<<doc_grid, 256, 0, stream>>>(
        docH, docH0, p_gW1, gb1, nullptr, nullptr, nullptr, nullptr, t1, D_);
    gemm_mfma<2, 24, 12, 12, false, false><<<doc_grid, 256, 0, stream>>>(
        t1, nullptr, p_gW2, gb2, nullptr, nullptr, docH, docH0, dmix, D_);
    gemm_mfma<3, 24, 12, 12, false, false><<<doc_grid, 256, 0, stream>>>(
        dmix, nullptr, p_mW1, mb1, mg, mbn, nullptr, nullptr, un, D_);
    gemm_mfma<4, 12, 12, 12, false, false><<<doc_grid, 256, 0, stream>>>(
        un, nullptr, p_mW2, mb2, cb, nullptr, cW, nullptr, logits, D_);
}

// Round 9
// 1129.142 us; speedup vs baseline: 2.0956x; 1.5477x over previous
//
#include <hip/hip_runtime.h>
#include <hip/hip_fp16.h>

#define HD 384
#define HHD 192
#define TPR 96
#define RPB 4
#define ECHUNK 128

using bf16x8 = __attribute__((ext_vector_type(8))) short;
using f32x4  = __attribute__((ext_vector_type(4))) float;

__device__ __forceinline__ float gelu_f(float x) {
    return 0.5f * x * (1.0f + erff(x * 0.70710678118654752f));
}

__device__ __forceinline__ float sigmoid_f(float x) {
    return 1.0f / (1.0f + expf(-x));
}

__device__ __forceinline__ void ld_h4(const __half2* p, float2& lo, float2& hi) {
    uint2 raw = *reinterpret_cast<const uint2*>(p);
    lo = __half22float2(*reinterpret_cast<const __half2*>(&raw.x));
    hi = __half22float2(*reinterpret_cast<const __half2*>(&raw.y));
}

// ---------------- CSR build ----------------
__global__ __launch_bounds__(256) void hist_rows(
        const int* __restrict__ rows, int* __restrict__ cnt, int nnz) {
    int e = blockIdx.x * blockDim.x + threadIdx.x;
    if (e < nnz) atomicAdd(&cnt[rows[e]], 1);
}

__global__ __launch_bounds__(256) void scan_local(
        const int* __restrict__ cnt, int* __restrict__ rp,
        int* __restrict__ bsum, int n) {
    __shared__ int wsum[4];
    int i = blockIdx.x * 256 + threadIdx.x;
    int lane = threadIdx.x & 63, wv = threadIdx.x >> 6;
    int v = (i < n) ? cnt[i] : 0;
    int s = v;
    #pragma unroll
    for (int o = 1; o < 64; o <<= 1) {
        int t = __shfl_up(s, o);
        if (lane >= o) s += t;
    }
    if (lane == 63) wsum[wv] = s;
    __syncthreads();
    int woff = 0;
    for (int w = 0; w < wv; ++w) woff += wsum[w];
    if (i < n) rp[i] = woff + s - v;
    if (threadIdx.x == 255) bsum[blockIdx.x] = woff + s;
}

__global__ __launch_bounds__(256) void scan_bsums(
        const int* __restrict__ bsum, int* __restrict__ boff,
        int nb, int* __restrict__ total_out) {
    __shared__ int tmp[256];
    int tid = threadIdx.x;
    int v = (tid < nb) ? bsum[tid] : 0;
    tmp[tid] = v;
    __syncthreads();
    for (int o = 1; o < 256; o <<= 1) {
        int t = (tid >= o) ? tmp[tid - o] : 0;
        __syncthreads();
        tmp[tid] += t;
        __syncthreads();
    }
    if (tid < nb) boff[tid] = tmp[tid] - v;
    if (tid == nb - 1) *total_out = tmp[tid];
}

__global__ __launch_bounds__(256) void scan_add(
        int* __restrict__ rp, const int* __restrict__ boff, int n) {
    int i = blockIdx.x * 256 + threadIdx.x;
    if (i < n) rp[i] += boff[i >> 8];
}

__global__ __launch_bounds__(256) void csr_scatter(
        const int* __restrict__ rows, const int* __restrict__ cols,
        const float* __restrict__ vals, const int* __restrict__ rp,
        int* __restrict__ fill, int* __restrict__ cp,
        float* __restrict__ vp, int nnz) {
    int e = blockIdx.x * blockDim.x + threadIdx.x;
    if (e >= nnz) return;
    int r = rows[e];
    int pos = rp[r] + atomicAdd(&fill[r], 1);
    cp[pos] = cols[e];
    vp[pos] = vals[e];
}

// ---------------- fp32 -> fp16 convert ----------------
__global__ __launch_bounds__(256) void cvt_fp16(
        const float* __restrict__ in, __half2* __restrict__ out, int n2) {
    int i = blockIdx.x * blockDim.x + threadIdx.x;
    if (i >= n2) return;
    float2 v = reinterpret_cast<const float2*>(in)[i];
    out[i] = __floats2half2_rn(v.x, v.y);
}

// ---------------- SpMM (CSR gather, fp16 table, fp16 out) ----------------
// 4 rows/block, 96 threads/row, 8B loads/lane, LDS-staged edges, unroll x4.
__global__ __launch_bounds__(384) void spmm_h2(
        const int* __restrict__ rp, const int* __restrict__ cp,
        const float* __restrict__ vp, const __half2* __restrict__ in,
        __half2* __restrict__ out, int nrows) {
    __shared__ int   lc[RPB][ECHUNK];
    __shared__ float lv[RPB][ECHUNK];
    __shared__ int maxlen_s;
    const int rr = threadIdx.x / TPR;
    const int t  = threadIdx.x % TPR;
    const int r  = blockIdx.x * RPB + rr;
    int s = 0, len = 0;
    if (r < nrows) { s = rp[r]; len = rp[r + 1] - s; }
    if (threadIdx.x == 0) maxlen_s = 0;
    __syncthreads();
    if (t == 0) atomicMax(&maxlen_s, len);
    __syncthreads();
    const int nch = (maxlen_s + ECHUNK - 1) / ECHUNK;
    float a0 = 0.f, a1 = 0.f, a2 = 0.f, a3 = 0.f;
    for (int ch = 0; ch < nch; ++ch) {
        const int base = ch * ECHUNK;
        const int tile = min(ECHUNK, len - base);
        for (int i = t; i < tile; i += TPR) {
            lc[rr][i] = cp[s + base + i];
            lv[rr][i] = vp[s + base + i];
        }
        __syncthreads();
        int p = 0;
        for (; p + 4 <= tile; p += 4) {
            int   c0 = lc[rr][p],     c1 = lc[rr][p + 1];
            int   c2 = lc[rr][p + 2], c3 = lc[rr][p + 3];
            float v0 = lv[rr][p],     v1 = lv[rr][p + 1];
            float v2 = lv[rr][p + 2], v3 = lv[rr][p + 3];
            float2 x0l, x0h, x1l, x1h, x2l, x2h, x3l, x3h;
            ld_h4(in + (size_t)c0 * HHD + 2 * t, x0l, x0h);
            ld_h4(in + (size_t)c1 * HHD + 2 * t, x1l, x1h);
            ld_h4(in + (size_t)c2 * HHD + 2 * t, x2l, x2h);
            ld_h4(in + (size_t)c3 * HHD + 2 * t, x3l, x3h);
            a0 = fmaf(v0, x0l.x, a0); a1 = fmaf(v0, x0l.y, a1);
            a2 = fmaf(v0, x0h.x, a2); a3 = fmaf(v0, x0h.y, a3);
            a0 = fmaf(v1, x1l.x, a0); a1 = fmaf(v1, x1l.y, a1);
            a2 = fmaf(v1, x1h.x, a2); a3 = fmaf(v1, x1h.y, a3);
            a0 = fmaf(v2, x2l.x, a0); a1 = fmaf(v2, x2l.y, a1);
            a2 = fmaf(v2, x2h.x, a2); a3 = fmaf(v2, x2h.y, a3);
            a0 = fmaf(v3, x3l.x, a0); a1 = fmaf(v3, x3l.y, a1);
            a2 = fmaf(v3, x3h.x, a2); a3 = fmaf(v3, x3h.y, a3);
        }
        for (; p < tile; ++p) {
            int c = lc[rr][p];
            float v = lv[rr][p];
            float2 xl, xh;
            ld_h4(in + (size_t)c * HHD + 2 * t, xl, xh);
            a0 = fmaf(v, xl.x, a0); a1 = fmaf(v, xl.y, a1);
            a2 = fmaf(v, xh.x, a2); a3 = fmaf(v, xh.y, a3);
        }
        __syncthreads();
    }
    if (r < nrows) {
        __half2 o0 = __floats2half2_rn(a0, a1);
        __half2 o1 = __floats2half2_rn(a2, a3);
        uint2 packed;
        packed.x = *reinterpret_cast<unsigned*>(&o0);
        packed.y = *reinterpret_cast<unsigned*>(&o1);
        *reinterpret_cast<uint2*>(out + (size_t)r * HHD + 2 * t) = packed;
    }
}

// ---------------- fused doc SpMM: docH0 = X@emb, docH = 0.35*docH0 + 0.65*X@h3 ----
__global__ __launch_bounds__(384) void spmm_doc2(
        const int* __restrict__ rp, const int* __restrict__ cp,
        const float* __restrict__ vp,
        const __half2* __restrict__ inH, const __half2* __restrict__ inE,
        float* __restrict__ docH, float* __restrict__ docH0, int nrows) {
    __shared__ int   lc[RPB][ECHUNK];
    __shared__ float lv[RPB][ECHUNK];
    __shared__ int maxlen_s;
    const int rr = threadIdx.x / TPR;
    const int t  = threadIdx.x % TPR;
    const int r  = blockIdx.x * RPB + rr;
    int s = 0, len = 0;
    if (r < nrows) { s = rp[r]; len = rp[r + 1] - s; }
    if (threadIdx.x == 0) maxlen_s = 0;
    __syncthreads();
    if (t == 0) atomicMax(&maxlen_s, len);
    __syncthreads();
    const int nch = (maxlen_s + ECHUNK - 1) / ECHUNK;
    float h0 = 0.f, h1 = 0.f, h2 = 0.f, h3 = 0.f;
    float e0 = 0.f, e1 = 0.f, e2 = 0.f, e3 = 0.f;
    for (int ch = 0; ch < nch; ++ch) {
        const int base = ch * ECHUNK;
        const int tile = min(ECHUNK, len - base);
        for (int i = t; i < tile; i += TPR) {
            lc[rr][i] = cp[s + base + i];
            lv[rr][i] = vp[s + base + i];
        }
        __syncthreads();
        int p = 0;
        for (; p + 2 <= tile; p += 2) {
            int   c0 = lc[rr][p], c1 = lc[rr][p + 1];
            float v0 = lv[rr][p], v1 = lv[rr][p + 1];
            float2 ha0, hb0, ea0, eb0, ha1, hb1, ea1, eb1;
            ld_h4(inH + (size_t)c0 * HHD + 2 * t, ha0, hb0);
            ld_h4(inE + (size_t)c0 * HHD + 2 * t, ea0, eb0);
            ld_h4(inH + (size_t)c1 * HHD + 2 * t, ha1, hb1);
            ld_h4(inE + (size_t)c1 * HHD + 2 * t, ea1, eb1);
            h0 = fmaf(v0, ha0.x, h0); h1 = fmaf(v0, ha0.y, h1);
            h2 = fmaf(v0, hb0.x, h2); h3 = fmaf(v0, hb0.y, h3);
            e0 = fmaf(v0, ea0.x, e0); e1 = fmaf(v0, ea0.y, e1);
            e2 = fmaf(v0, eb0.x, e2); e3 = fmaf(v0, eb0.y, e3);
            h0 = fmaf(v1, ha1.x, h0); h1 = fmaf(v1, ha1.y, h1);
            h2 = fmaf(v1, hb1.x, h2); h3 = fmaf(v1, hb1.y, h3);
            e0 = fmaf(v1, ea1.x, e0); e1 = fmaf(v1, ea1.y, e1);
            e2 = fmaf(v1, eb1.x, e2); e3 = fmaf(v1, eb1.y, e3);
        }
        for (; p < tile; ++p) {
            int c = lc[rr][p];
            float v = lv[rr][p];
            float2 ha, hb, ea, eb;
            ld_h4(inH + (size_t)c * HHD + 2 * t, ha, hb);
            ld_h4(inE + (size_t)c * HHD + 2 * t, ea, eb);
            h0 = fmaf(v, ha.x, h0); h1 = fmaf(v, ha.y, h1);
            h2 = fmaf(v, hb.x, h2); h3 = fmaf(v, hb.y, h3);
            e0 = fmaf(v, ea.x, e0); e1 = fmaf(v, ea.y, e1);
            e2 = fmaf(v, eb.x, e2); e3 = fmaf(v, eb.y, e3);
        }
        __syncthreads();
    }
    if (r < nrows) {
        float4 ev = make_float4(e0, e1, e2, e3);
        float4 hv = make_float4(0.35f * e0 + 0.65f * h0, 0.35f * e1 + 0.65f * h1,
                                0.35f * e2 + 0.65f * h2, 0.35f * e3 + 0.65f * h3);
        *reinterpret_cast<float4*>(docH0 + (size_t)r * HD + 4 * t) = ev;
        *reinterpret_cast<float4*>(docH  + (size_t)r * HD + 4 * t) = hv;
    }
}

// ---------------- weight pack: fp32 [K,N] -> fragment-layout hi/lo bf16 ----------------
__global__ __launch_bounds__(256) void pack_w(
        const float* __restrict__ W, unsigned short* __restrict__ out,
        int KS, int NS, int N) {
    int t = blockIdx.x * 256 + threadIdx.x;
    int total = KS * NS * 64;
    if (t >= total) return;
    int l = t & 63;
    int ns = (t >> 6) % NS;
    int ks = t / (64 * NS);
    int col = ns * 16 + (l & 15);
    int k0 = ks * 32 + 8 * (l >> 4);
    size_t obase = (size_t)t * 8;
    size_t pstride = (size_t)KS * NS * 512;
    #pragma unroll
    for (int e = 0; e < 8; ++e) {
        float f = W[(size_t)(k0 + e) * N + col];
        unsigned u = __float_as_uint(f);
        unsigned short h = (unsigned short)(u >> 16);
        float r = f - __uint_as_float(u & 0xFFFF0000u);
        unsigned short lo = (unsigned short)(__float_as_uint(r) >> 16);
        out[obase + e] = (unsigned short)h;
        out[pstride + obase + e] = lo;
    }
}

__device__ __forceinline__ void splitf(const float* f, bf16x8& h, bf16x8& l) {
    #pragma unroll
    for (int e = 0; e < 8; ++e) {
        unsigned u = __float_as_uint(f[e]);
        h[e] = (short)(unsigned short)(u >> 16);
        float r = f[e] - __uint_as_float(u & 0xFFFF0000u);
        l[e] = (short)(unsigned short)(__float_as_uint(r) >> 16);
    }
}

// ---------------- split-bf16 MFMA GEMM; 16-row M-tile/block, N split over 4 waves ----
template<int MODE, int NS, int KS, int KSPLIT, bool A16, bool OUT16>
__global__ __launch_bounds__(256) void gemm_mfma(
        const float* __restrict__ A1, const float* __restrict__ A2,
        const unsigned short* __restrict__ Wp,
        const float* __restrict__ bias, const float* __restrict__ gamma,
        const float* __restrict__ beta,
        const float* __restrict__ aux1, const float* __restrict__ aux2,
        float* __restrict__ out, int M) {
    constexpr int N = NS * 16;
    constexpr int NSW = NS / 4;
    const int tid = threadIdx.x;
    const int wave = tid >> 6, l = tid & 63;
    const int row_base = blockIdx.x * 16;
    const int arow = row_base + (l & 15);
    const bool arow_ok = arow < M;
    const int koff = 8 * (l >> 4);
    const size_t pstride = (size_t)KS * NS * 512;

    __shared__ float ps[4][16], pq[4][16];
    __shared__ float mean_s[16], rstd_s[16];
    __shared__ float plg[4][16][2];

    f32x4 acc[NSW];
    #pragma unroll
    for (int ns = 0; ns < NSW; ++ns)
        acc[ns] = f32x4{0.f, 0.f, 0.f, 0.f};

    for (int ks = 0; ks < KS; ++ks) {
        const float* Ap;
        int ksl;
        if (ks < KSPLIT) { Ap = A1; ksl = ks; }
        else             { Ap = A2; ksl = ks - KSPLIT; }
        bf16x8 ah, al;
        if (arow_ok) {
            float f[8];
            if constexpr (A16) {
                const __half2* src = reinterpret_cast<const __half2*>(Ap)
                                     + ((size_t)arow * HD + ksl * 32 + koff) / 2;
                #pragma unroll
                for (int e = 0; e < 4; ++e) {
                    float2 v = __half22float2(src[e]);
                    f[2 * e]     = v.x;
                    f[2 * e + 1] = v.y;
                }
            } else {
                const float* src = Ap + (size_t)arow * HD + ksl * 32 + koff;
                float4 a0 = *reinterpret_cast<const float4*>(src);
                float4 a1 = *reinterpret_cast<const float4*>(src + 4);
                f[0] = a0.x; f[1] = a0.y; f[2] = a0.z; f[3] = a0.w;
                f[4] = a1.x; f[5] = a1.y; f[6] = a1.z; f[7] = a1.w;
            }
            splitf(f, ah, al);
        } else {
            #pragma unroll
            for (int e = 0; e < 8; ++e) { ah[e] = 0; al[e] = 0; }
        }
        const unsigned short* Bp = Wp + (size_t)ks * NS * 512
                                   + (size_t)wave * NSW * 512 + (size_t)l * 8;
        #pragma unroll
        for (int ns = 0; ns < NSW; ++ns) {
            bf16x8 bh = *reinterpret_cast<const bf16x8*>(Bp + ns * 512);
            bf16x8 bl = *reinterpret_cast<const bf16x8*>(Bp + pstride + ns * 512);
            acc[ns] = __builtin_amdgcn_mfma_f32_16x16x32_bf16(ah, bh, acc[ns], 0, 0, 0);
            acc[ns] = __builtin_amdgcn_mfma_f32_16x16x32_bf16(al, bh, acc[ns], 0, 0, 0);
            acc[ns] = __builtin_amdgcn_mfma_f32_16x16x32_bf16(ah, bl, acc[ns], 0, 0, 0);
        }
    }

    const int col_lane = l & 15;
    const int g4 = (l >> 4) * 4;
    constexpr float invN = 1.0f / (float)N;

    if constexpr (MODE == 0 || MODE == 3) {
        if constexpr (MODE == 3) {
            #pragma unroll
            for (int ns = 0; ns < NSW; ++ns) {
                float bb = bias[(wave * NSW + ns) * 16 + col_lane];
                #pragma unroll
                for (int r = 0; r < 4; ++r)
                    acc[ns][r] = gelu_f(acc[ns][r] + bb);
            }
        }
        float s[4] = {0.f, 0.f, 0.f, 0.f}, q[4] = {0.f, 0.f, 0.f, 0.f};
        #pragma unroll
        for (int ns = 0; ns < NSW; ++ns)
            #pragma unroll
            for (int r = 0; r < 4; ++r) {
                float v = acc[ns][r];
                s[r] += v;
                q[r] += v * v;
            }
        #pragma unroll
        for (int r = 0; r < 4; ++r) {
            #pragma unroll
            for (int m = 1; m < 16; m <<= 1) {
                s[r] += __shfl_xor(s[r], m);
                q[r] += __shfl_xor(q[r], m);
            }
        }
        if (col_lane == 0) {
            #pragma unroll
            for (int r = 0; r < 4; ++r) {
                ps[wave][g4 + r] = s[r];
                pq[wave][g4 + r] = q[r];
            }
        }
        __syncthreads();
        if (tid < 16) {
            float ss = ps[0][tid] + ps[1][tid] + ps[2][tid] + ps[3][tid];
            float qq = pq[0][tid] + pq[1][tid] + pq[2][tid] + pq[3][tid];
            float m = ss * invN;
            mean_s[tid] = m;
            rstd_s[tid] = rsqrtf(qq * invN - m * m + 1e-5f);
        }
        __syncthreads();
        #pragma unroll
        for (int ns = 0; ns < NSW; ++ns) {
            int col = (wave * NSW + ns) * 16 + col_lane;
            float gg = gamma[col], bb = beta[col];
            #pragma unroll
            for (int r = 0; r < 4; ++r) {
                int row = row_base + g4 + r;
                if (row < M) {
                    float y = (acc[ns][r] - mean_s[g4 + r]) * rstd_s[g4 + r] * gg + bb;
                    if constexpr (MODE == 0) {
                        y = gelu_f(y);
                        if constexpr (OUT16)
                            reinterpret_cast<__half*>(out)[(size_t)row * N + col] =
                                __float2half(y);
                        else
                            out[(size_t)row * N + col] = y;
                    } else {
                        out[(size_t)row * N + col] = y;
                    }
                }
            }
        }
    } else if constexpr (MODE == 1) {
        #pragma unroll
        for (int ns = 0; ns < NSW; ++ns) {
            int col = (wave * NSW + ns) * 16 + col_lane;
            float bb = bias[col];
            #pragma unroll
            for (int r = 0; r < 4; ++r) {
                int row = row_base + g4 + r;
                if (row < M)
                    out[(size_t)row * N + col] = gelu_f(acc[ns][r] + bb);
            }
        }
    } else if constexpr (MODE == 2) {
        #pragma unroll
        for (int ns = 0; ns < NSW; ++ns) {
            int col = (wave * NSW + ns) * 16 + col_lane;
            float bb = bias[col];
            #pragma unroll
            for (int r = 0; r < 4; ++r) {
                int row = row_base + g4 + r;
                if (row < M) {
                    float g = sigmoid_f(acc[ns][r] + bb);
                    float h1 = aux1[(size_t)row * N + col];
                    float h0 = aux2[(size_t)row * N + col];
                    out[(size_t)row * N + col] = g * h1 + (1.0f - g) * h0;
                }
            }
        }
    } else if constexpr (MODE == 4) {
        float lg0[4] = {0.f, 0.f, 0.f, 0.f}, lg1[4] = {0.f, 0.f, 0.f, 0.f};
        #pragma unroll
        for (int ns = 0; ns < NSW; ++ns) {
            int col = (wave * NSW + ns) * 16 + col_lane;
            float bb = bias[col];
            float c0 = aux1[col * 2 + 0];
            float c1 = aux1[col * 2 + 1];
            #pragma unroll
            for (int r = 0; r < 4; ++r) {
                float v = gelu_f(acc[ns][r] + bb);
                lg0[r] = fmaf(v, c0, lg0[r]);
                lg1[r] = fmaf(v, c1, lg1[r]);
            }
        }
        #pragma unroll
        for (int r = 0; r < 4; ++r) {
            #pragma unroll
            for (int m = 1; m < 16; m <<= 1) {
                lg0[r] += __shfl_xor(lg0[r], m);
                lg1[r] += __shfl_xor(lg1[r], m);
            }
        }
        if (col_lane == 0) {
            #pragma unroll
            for (int r = 0; r < 4; ++r) {
                plg[wave][g4 + r][0] = lg0[r];
                plg[wave][g4 + r][1] = lg1[r];
            }
        }
        __syncthreads();
        if (tid < 32) {
            int rloc = tid >> 1, c = tid & 1;
            int row = row_base + rloc;
            if (row < M) {
                float t = plg[0][rloc][c] + plg[1][rloc][c]
                        + plg[2][rloc][c] + plg[3][rloc][c];
                out[(size_t)row * 2 + c] = t + gamma[c];
            }
        }
    }
}

static void build_csr(const int* rows, const int* cols, const float* vals,
                      int nnz, int n, int* rp, int* cp, float* vp,
                      int* cnt, int* bsum, int* boff, hipStream_t stream) {
    hipMemsetAsync(cnt, 0, (size_t)n * sizeof(int), stream);
    hist_rows<<<(nnz + 255) / 256, 256, 0, stream>>>(rows, cnt, nnz);
    int nb = (n + 255) / 256;
    scan_local<<<nb, 256, 0, stream>>>(cnt, rp, bsum, n);
    scan_bsums<<<1, 256, 0, stream>>>(bsum, boff, nb, rp + n);
    scan_add<<<nb, 256, 0, stream>>>(rp, boff, n);
    hipMemsetAsync(cnt, 0, (size_t)n * sizeof(int), stream);
    csr_scatter<<<(nnz + 255) / 256, 256, 0, stream>>>(rows, cols, vals, rp, cnt, cp, vp, nnz);
}

extern "C" void kernel_launch(void* const* d_in, const int* in_sizes, int n_in,
                              void* d_out, int out_size, void* d_ws, size_t ws_size,
                              hipStream_t stream) {
    const int*   A_rows = (const int*)  d_in[0];
    const int*   A_cols = (const int*)  d_in[1];
    const float* A_vals = (const float*)d_in[2];
    const int*   X_rows = (const int*)  d_in[3];
    const int*   X_cols = (const int*)  d_in[4];
    const float* X_vals = (const float*)d_in[5];
    const float* emb    = (const float*)d_in[7];
    const float* W1     = (const float*)d_in[8];
    const float* W2     = (const float*)d_in[9];
    const float* W3     = (const float*)d_in[10];
    const float* g1     = (const float*)d_in[11];
    const float* b1     = (const float*)d_in[12];
    const float* g2     = (const float*)d_in[13];
    const float* b2     = (const float*)d_in[14];
    const float* g3     = (const float*)d_in[15];
    const float* b3     = (const float*)d_in[16];
    const float* mW1    = (const float*)d_in[17];
    const float* mb1    = (const float*)d_in[18];
    const float* mg     = (const float*)d_in[19];
    const float* mbn    = (const float*)d_in[20];
    const float* mW2    = (const float*)d_in[21];
    const float* mb2    = (const float*)d_in[22];
    const float* cW     = (const float*)d_in[23];
    const float* cb     = (const float*)d_in[24];
    const float* gW1    = (const float*)d_in[25];
    const float* gb1    = (const float*)d_in[26];
    const float* gW2    = (const float*)d_in[27];
    const float* gb2    = (const float*)d_in[28];

    const int E_   = in_sizes[0];
    const int NNZ_ = in_sizes[3];
    const int N_   = in_sizes[7] / HD;
    const int D_   = out_size / 2;

    // ---- workspace layout ----
    __half2* emb16 = (__half2*)d_ws;                   // [N,H] fp16 | later t1 [D,H] f32
    __half2* Ba    = emb16 + (size_t)N_ * HHD;         // ping     | later docH/un f32
    __half2* Bb    = Ba    + (size_t)N_ * HHD;         // pong     | later dmix f32
    float* docH0 = (float*)(Bb + (size_t)N_ * HHD);    // [D,H] f32
    int*   A_rp = (int*)(docH0 + (size_t)D_ * HD);
    int*   A_cp = A_rp + (N_ + 1);
    float* A_vp = (float*)(A_cp + E_);
    int*   X_rp = (int*)(A_vp + E_);
    int*   X_cp = X_rp + (D_ + 1);
    float* X_vp = (float*)(X_cp + NNZ_);
    int*   cnt  = (int*)(X_vp + NNZ_);
    int*   bsum = cnt + N_;
    int*   boff = bsum + 256;
    size_t pk_off = ((size_t)(boff + 256 - (int*)d_ws) + 7) & ~(size_t)7;
    unsigned short* packs = (unsigned short*)((float*)d_ws + pk_off);
    const size_t SZ_SQ = (size_t)2 * HD * HD;
    unsigned short* p_W1  = packs;
    unsigned short* p_W2  = p_W1  + SZ_SQ;
    unsigned short* p_W3  = p_W2  + SZ_SQ;
    unsigned short* p_gW2 = p_W3  + SZ_SQ;
    unsigned short* p_mW1 = p_gW2 + SZ_SQ;
    unsigned short* p_gW1 = p_mW1 + SZ_SQ;
    unsigned short* p_mW2 = p_gW1 + (size_t)2 * 2 * HD * HD;

    // doc-phase fp32 aliases
    float* docH  = (float*)Ba;
    float* t1    = (float*)emb16;
    float* dmix  = (float*)Bb;
    float* un    = (float*)Ba;
    float* logits = (float*)d_out;

    const int word_grid = (N_ + 15) / 16;
    const int doc_grid  = (D_ + 15) / 16;
    const int spmm_word_grid = (N_ + RPB - 1) / RPB;
    const int spmm_doc_grid  = (D_ + RPB - 1) / RPB;

    // ---- pack weights ----
    pack_w<<<(12 * 24 * 64 + 255) / 256, 256, 0, stream>>>(W1,  p_W1,  12, 24, HD);
    pack_w<<<(12 * 24 * 64 + 255) / 256, 256, 0, stream>>>(W2,  p_W2,  12, 24, HD);
    pack_w<<<(12 * 24 * 64 + 255) / 256, 256, 0, stream>>>(W3,  p_W3,  12, 24, HD);
    pack_w<<<(12 * 24 * 64 + 255) / 256, 256, 0, stream>>>(gW2, p_gW2, 12, 24, HD);
    pack_w<<<(12 * 24 * 64 + 255) / 256, 256, 0, stream>>>(mW1, p_mW1, 12, 24, HD);
    pack_w<<<(24 * 24 * 64 + 255) / 256, 256, 0, stream>>>(gW1, p_gW1, 24, 24, HD);
    pack_w<<<(12 * 12 * 64 + 255) / 256, 256, 0, stream>>>(mW2, p_mW2, 12, 12, HHD);

    // ---- emb -> fp16 ----
    cvt_fp16<<<((N_ * HHD) + 255) / 256, 256, 0, stream>>>(emb, emb16, N_ * HHD);

    // ---- build CSR ----
    build_csr(A_rows, A_cols, A_vals, E_, N_, A_rp, A_cp, A_vp, cnt, bsum, boff, stream);
    build_csr(X_rows, X_cols, X_vals, NNZ_, D_, X_rp, X_cp, X_vp, cnt, bsum, boff, stream);

    // ---- GCN blocks (fp16 ping-pong) ----
    spmm_h2<<<spmm_word_grid, 384, 0, stream>>>(A_rp, A_cp, A_vp, emb16, Ba, N_);
    gemm_mfma<0, 24, 12, 12, true, true><<<word_grid, 256, 0, stream>>>(
        (const float*)Ba, nullptr, p_W1, nullptr, g1, b1, nullptr, nullptr, (float*)Bb, N_);
    spmm_h2<<<spmm_word_grid, 384, 0, stream>>>(A_rp, A_cp, A_vp, Bb, Ba, N_);
    gemm_mfma<0, 24, 12, 12, true, true><<<word_grid, 256, 0, stream>>>(
        (const float*)Ba, nullptr, p_W2, nullptr, g2, b2, nullptr, nullptr, (float*)Bb, N_);
    spmm_h2<<<spmm_word_grid, 384, 0, stream>>>(A_rp, A_cp, A_vp, Bb, Ba, N_);
    gemm_mfma<0, 24, 12, 12, true, true><<<word_grid, 256, 0, stream>>>(
        (const float*)Ba, nullptr, p_W3, nullptr, g3, b3, nullptr, nullptr, (float*)Bb, N_);

    // ---- fused doc aggregation ----
    spmm_doc2<<<spmm_doc_grid, 384, 0, stream>>>(X_rp, X_cp, X_vp, Bb, emb16,
                                                 docH, docH0, D_);

    // ---- doc head ----
    gemm_mfma<1, 24, 24, 12, false, false><<<doc_grid, 256, 0, stream>>>(
        docH, docH0, p_gW1, gb1, nullptr, nullptr, nullptr, nullptr, t1, D_);
    gemm_mfma<2, 24, 12, 12, false, false><<<doc_grid, 256, 0, stream>>>(
        t1, nullptr, p_gW2, gb2, nullptr, nullptr, docH, docH0, dmix, D_);
    gemm_mfma<3, 24, 12, 12, false, false><<<doc_grid, 256, 0, stream>>>(
        dmix, nullptr, p_mW1, mb1, mg, mbn, nullptr, nullptr, un, D_);
    gemm_mfma<4, 12, 12, 12, false, false><<<doc_grid, 256, 0, stream>>>(
        un, nullptr, p_mW2, mb2, cb, nullptr, cW, nullptr, logits, D_);
}